// Round 1
// baseline (590.296 us; speedup 1.0000x reference)
//
#include <hip/hip_runtime.h>

#define H 128

typedef __attribute__((ext_vector_type(8))) short bf16x8;
typedef __attribute__((ext_vector_type(4))) float f32x4;

__device__ __forceinline__ unsigned short f2bf(float f) {
    unsigned u = __float_as_uint(f);
    u += 0x7FFFu + ((u >> 16) & 1u);
    return (unsigned short)(u >> 16);
}
__device__ __forceinline__ float bflo(unsigned v) { return __uint_as_float(v << 16); }
__device__ __forceinline__ float bfhi(unsigned v) { return __uint_as_float(v & 0xFFFF0000u); }

// ---- CSR build ----------------------------------------------------------
__global__ void k_count(const int* __restrict__ ei, int* __restrict__ counts, int E) {
    int e = blockIdx.x * blockDim.x + threadIdx.x;
    if (e < E) atomicAdd(&counts[ei[E + e]], 1);
}

__global__ void k_deg(const int* __restrict__ counts, float* __restrict__ dinv,
                      float* __restrict__ invdeg, int N) {
    int i = blockIdx.x * blockDim.x + threadIdx.x;
    if (i < N) {
        float d = (float)(counts[i] + 1);
        dinv[i] = rsqrtf(d);
        invdeg[i] = 1.0f / d;
    }
}

__global__ void k_scan1(const int* __restrict__ counts, int* __restrict__ rp,
                        int* __restrict__ bsum, int N) {
    __shared__ int sh[256];
    int tid = threadIdx.x;
    int idx = blockIdx.x * 256 + tid;
    int v = (idx < N) ? counts[idx] : 0;
    sh[tid] = v;
    __syncthreads();
    for (int off = 1; off < 256; off <<= 1) {
        int t = (tid >= off) ? sh[tid - off] : 0;
        __syncthreads();
        sh[tid] += t;
        __syncthreads();
    }
    if (idx < N) rp[idx] = sh[tid] - v;           // exclusive within block
    if (tid == 255) bsum[blockIdx.x] = sh[tid];   // block total
}

__global__ void k_scan2(const int* __restrict__ bsum, int* __restrict__ boff, int nb) {
    __shared__ int sh[512];
    int tid = threadIdx.x;
    int v = (tid < nb) ? bsum[tid] : 0;
    sh[tid] = v;
    __syncthreads();
    for (int off = 1; off < 512; off <<= 1) {
        int t = (tid >= off) ? sh[tid - off] : 0;
        __syncthreads();
        sh[tid] += t;
        __syncthreads();
    }
    boff[tid] = sh[tid] - v;                      // exclusive block offsets
}

__global__ void k_scan3(int* __restrict__ rp, const int* __restrict__ boff, int N, int E) {
    int idx = blockIdx.x * 256 + threadIdx.x;
    if (idx < N) rp[idx] += boff[blockIdx.x];
    if (idx == 0) rp[N] = E;
}

__global__ void k_fill(const int* __restrict__ ei, const float* __restrict__ dinv,
                       const int* __restrict__ rp, int* __restrict__ tmp,
                       int* __restrict__ csrc, float* __restrict__ cw, int E) {
    int e = blockIdx.x * blockDim.x + threadIdx.x;
    if (e < E) {
        int s = ei[e], d = ei[E + e];
        int p = rp[d] + atomicAdd(&tmp[d], 1);
        csrc[p] = s;
        cw[p] = dinv[s] * dinv[d];   // norm_e
    }
}

// ---- dtype prep ---------------------------------------------------------
__global__ void k_xbf(const float* __restrict__ x, unsigned* __restrict__ xb, int n2) {
    int i = blockIdx.x * blockDim.x + threadIdx.x;
    if (i < n2) {
        float2 v = ((const float2*)x)[i];
        xb[i] = (unsigned)f2bf(v.x) | ((unsigned)f2bf(v.y) << 16);
    }
}

// Wt[k][h][f] = W[k][f][h]  (bf16, transposed so MFMA B-frags are contiguous)
__global__ void k_wt(const float* __restrict__ W, unsigned short* __restrict__ Wt, int total) {
    int idx = blockIdx.x * blockDim.x + threadIdx.x;
    if (idx < total) {
        int k = idx >> 14;
        int f = (idx >> 7) & 127;
        int h = idx & 127;
        Wt[(k << 14) + (h << 7) + f] = f2bf(W[idx]);
    }
}

// WRt[k][f][c] = sum_h W[k][f][h] * R[k][c][h]  (cols >= ck zeroed)
// bias2[k*4+c] = sum_h b[k][h]*R[k][c][h] + r[k][c]; bias2[28..31]=0
__global__ void k_wrt(const float* __restrict__ W, const float* __restrict__ b,
                      const float* __restrict__ rs3w, const float* __restrict__ rs3b,
                      const float* __restrict__ rs2w, const float* __restrict__ rs2b,
                      float* __restrict__ WRt, float* __restrict__ bias2) {
    int tid = blockIdx.x * blockDim.x + threadIdx.x;
    if (tid >= 896) {
        if (tid < 900) bias2[28 + (tid - 896)] = 0.0f;
        return;
    }
    int k = tid >> 7, f = tid & 127;
    int ck = (k < 5) ? 3 : 2;
    const float* R = (k < 5) ? (rs3w + k * 3 * H) : (rs2w + (k - 5) * 2 * H);
    const float* Wk = W + (k << 14) + (f << 7);
    float s[4] = {0.f, 0.f, 0.f, 0.f};
    for (int h = 0; h < H; ++h) {
        float w = Wk[h];
        for (int c = 0; c < 3; ++c)
            if (c < ck) s[c] += w * R[c * H + h];
    }
    for (int c = 0; c < 4; ++c) WRt[(tid << 2) + c] = (c < ck) ? s[c] : 0.0f;
    if (f == 0) {
        const float* rb = (k < 5) ? (rs3b + k * 3) : (rs2b + (k - 5) * 2);
        const float* bk = b + k * H;
        for (int c = 0; c < 4; ++c) {
            float t = 0.0f;
            if (c < ck) {
                for (int h = 0; h < H; ++h) t += bk[h] * R[c * H + h];
                t += rb[c];
            }
            bias2[(k << 2) + c] = t;
        }
    }
}

// ---- aggregation 1: px = P_hat @ x (bf16 in, fp32 acc, bf16 out) --------
__global__ void __launch_bounds__(256) k_px(const unsigned* __restrict__ xb,
        const int* __restrict__ rp, const int* __restrict__ csrc,
        const float* __restrict__ cw, const float* __restrict__ invdeg,
        unsigned* __restrict__ pxb, int N) {
    int lane = threadIdx.x & 63;
    int wv = threadIdx.x >> 6;
    int i = blockIdx.x * 4 + wv;
    if (i >= N) return;
    int s = rp[i], e = rp[i + 1];
    float a0 = 0.0f, a1 = 0.0f;
    for (int base = s; base < e; base += 64) {
        int el = base + lane;
        bool ok = el < e;
        int j_l = ok ? csrc[el] : 0;
        float w_l = ok ? cw[el] : 0.0f;
        int cnt = e - base; if (cnt > 64) cnt = 64;
        for (int t = 0; t < cnt; t += 4) {
            int   j0 = __shfl(j_l, t),     j1 = __shfl(j_l, t + 1);
            int   j2 = __shfl(j_l, t + 2), j3 = __shfl(j_l, t + 3);
            float w0 = __shfl(w_l, t),     w1 = __shfl(w_l, t + 1);
            float w2 = __shfl(w_l, t + 2), w3 = __shfl(w_l, t + 3);
            unsigned v0 = xb[j0 * 64 + lane];
            unsigned v1 = xb[j1 * 64 + lane];
            unsigned v2 = xb[j2 * 64 + lane];
            unsigned v3 = xb[j3 * 64 + lane];
            a0 += w0 * bflo(v0); a1 += w0 * bfhi(v0);
            a0 += w1 * bflo(v1); a1 += w1 * bfhi(v1);
            a0 += w2 * bflo(v2); a1 += w2 * bfhi(v2);
            a0 += w3 * bflo(v3); a1 += w3 * bfhi(v3);
        }
    }
    unsigned vi = xb[i * 64 + lane];
    float id = invdeg[i];
    a0 += id * bflo(vi);
    a1 += id * bfhi(vi);
    pxb[i * 64 + lane] = (unsigned)f2bf(a0) | ((unsigned)f2bf(a1) << 16);
}

// ---- GEMM: u[:,k*4+c] = relu(px @ W_k + b_k) @ WRt_k  (MFMA bf16) -------
// Assumes N % 32 == 0 (N = 100000 = 3125*32).
__global__ void __launch_bounds__(256) k_gemm(const unsigned short* __restrict__ pxb,
        const unsigned short* __restrict__ Wt, const float* __restrict__ gb,
        const float* __restrict__ WRt, float* __restrict__ uall, int N) {
    __shared__ __align__(16) float red[4][32][4];
    int k = blockIdx.y;
    int bx = blockIdx.x;
    int w = threadIdx.x >> 6;
    int lane = threadIdx.x & 63;
    int quad = lane >> 4, l16 = lane & 15;
    const unsigned short* A = pxb + (size_t)bx * 32 * H;
    const unsigned short* B = Wt + (k << 14) + (w * 32) * H;
    f32x4 acc[2][2] = {};
#pragma unroll
    for (int kk = 0; kk < 4; ++kk) {
        int k0 = kk * 32 + quad * 8;
        bf16x8 a0 = *(const bf16x8*)(A + (l16) * H + k0);
        bf16x8 a1 = *(const bf16x8*)(A + (16 + l16) * H + k0);
        bf16x8 b0 = *(const bf16x8*)(B + (l16) * H + k0);
        bf16x8 b1 = *(const bf16x8*)(B + (16 + l16) * H + k0);
        acc[0][0] = __builtin_amdgcn_mfma_f32_16x16x32_bf16(a0, b0, acc[0][0], 0, 0, 0);
        acc[0][1] = __builtin_amdgcn_mfma_f32_16x16x32_bf16(a0, b1, acc[0][1], 0, 0, 0);
        acc[1][0] = __builtin_amdgcn_mfma_f32_16x16x32_bf16(a1, b0, acc[1][0], 0, 0, 0);
        acc[1][1] = __builtin_amdgcn_mfma_f32_16x16x32_bf16(a1, b1, acc[1][1], 0, 0, 0);
    }
    // epilogue: h1 = relu(s + bias); partial u = h1 * WRt (per-lane cols)
    int col0 = w * 32 + l16;
    float4 wr0 = *(const float4*)(WRt + ((k * H + col0) << 2));
    float4 wr1 = *(const float4*)(WRt + ((k * H + col0 + 16) << 2));
    float bi0 = gb[k * H + col0];
    float bi1 = gb[k * H + col0 + 16];
    float4 part[2][4];
#pragma unroll
    for (int ms = 0; ms < 2; ++ms)
#pragma unroll
        for (int r = 0; r < 4; ++r) {
            float h0 = fmaxf(acc[ms][0][r] + bi0, 0.0f);
            float h1 = fmaxf(acc[ms][1][r] + bi1, 0.0f);
            float4 p;
            p.x = h0 * wr0.x + h1 * wr1.x;
            p.y = h0 * wr0.y + h1 * wr1.y;
            p.z = h0 * wr0.z + h1 * wr1.z;
            p.w = h0 * wr0.w + h1 * wr1.w;
            part[ms][r] = p;
        }
    // reduce over the 16 lanes (cols) within each quad-group
#pragma unroll
    for (int mask = 1; mask <= 8; mask <<= 1) {
#pragma unroll
        for (int ms = 0; ms < 2; ++ms)
#pragma unroll
            for (int r = 0; r < 4; ++r) {
                float4 p = part[ms][r];
                p.x += __shfl_xor(p.x, mask);
                p.y += __shfl_xor(p.y, mask);
                p.z += __shfl_xor(p.z, mask);
                p.w += __shfl_xor(p.w, mask);
                part[ms][r] = p;
            }
    }
    if (l16 == 0) {
#pragma unroll
        for (int ms = 0; ms < 2; ++ms)
#pragma unroll
            for (int r = 0; r < 4; ++r) {
                int row = ms * 16 + quad * 4 + r;
                *(float4*)&red[w][row][0] = part[ms][r];
            }
    }
    __syncthreads();
    int t = threadIdx.x;
    if (t < 128) {
        int row = t >> 2, c = t & 3;
        float s = red[0][row][c] + red[1][row][c] + red[2][row][c] + red[3][row][c];
        uall[(size_t)(bx * 32 + row) * 32 + (k << 2) + c] = s;
    }
}

// ---- aggregation 2 + softmax: out = softmax(P_hat @ u + bias2) ----------
__global__ void __launch_bounds__(256) k_out(const float* __restrict__ uall,
        const int* __restrict__ rp, const int* __restrict__ csrc,
        const float* __restrict__ cw, const float* __restrict__ invdeg,
        const float* __restrict__ bias2, float* __restrict__ out, int N) {
    int lane = threadIdx.x & 63;
    int wv = threadIdx.x >> 6;
    int i = blockIdx.x * 4 + wv;
    if (i >= N) return;
    int c32 = lane & 31;
    int half = lane >> 5;
    int s = rp[i], e = rp[i + 1];
    float acc = 0.0f;
    for (int base = s; base < e; base += 64) {
        int el = base + lane;
        bool ok = el < e;
        int j_l = ok ? csrc[el] : 0;
        float w_l = ok ? cw[el] : 0.0f;
        int cnt = e - base; if (cnt > 64) cnt = 64;
        for (int t = 0; t < cnt; t += 2) {
            int   j0 = __shfl(j_l, t);     float w0 = __shfl(w_l, t);
            int   j1 = __shfl(j_l, t + 1); float w1 = __shfl(w_l, t + 1);
            int   jj = half ? j1 : j0;
            float ww = half ? w1 : w0;
            acc += ww * uall[jj * 32 + c32];
        }
    }
    acc += __shfl_xor(acc, 32);
    float v = acc + invdeg[i] * uall[i * 32 + c32] + bias2[c32];
    int kk = c32 >> 2, cc = c32 & 3;
    int qb = lane & ~3;
    float v0 = __shfl(v, qb), v1 = __shfl(v, qb + 1), v2 = __shfl(v, qb + 2);
    int ck = (kk < 5) ? 3 : 2;
    float m = fmaxf(v0, v1);
    if (ck == 3) m = fmaxf(m, v2);
    float sum = __expf(v0 - m) + __expf(v1 - m) + ((ck == 3) ? __expf(v2 - m) : 0.0f);
    float r = __expf(v - m) / sum;
    if (half == 0 && c32 < 28 && cc < ck) {
        size_t basek = (kk < 5) ? (size_t)kk * 3 * N
                                : (size_t)15 * N + (size_t)(kk - 5) * 2 * N;
        out[basek + (size_t)i * ck + cc] = r;
    }
}

// ---- launch -------------------------------------------------------------
extern "C" void kernel_launch(void* const* d_in, const int* in_sizes, int n_in,
                              void* d_out, int out_size, void* d_ws, size_t ws_size,
                              hipStream_t stream) {
    (void)n_in; (void)out_size; (void)ws_size;
    const float* x   = (const float*)d_in[0];
    const int*   ei  = (const int*)d_in[1];
    const float* gw  = (const float*)d_in[2];
    const float* gb  = (const float*)d_in[3];
    const float* r3w = (const float*)d_in[4];
    const float* r3b = (const float*)d_in[5];
    const float* r2w = (const float*)d_in[6];
    const float* r2b = (const float*)d_in[7];
    float* out = (float*)d_out;
    int N = in_sizes[0] / H;   // 100000
    int E = in_sizes[1] / 2;   // 1600000

    char* p = (char*)d_ws;
    auto alloc = [&](size_t bytes) {
        char* q = p;
        p += (bytes + 255) & ~(size_t)255;
        return q;
    };
    unsigned*       xb     = (unsigned*)alloc((size_t)N * 64 * 4);        // x  bf16 [N,128]
    unsigned*       pxb    = (unsigned*)alloc((size_t)N * 64 * 4);        // px bf16 [N,128]
    unsigned short* Wt     = (unsigned short*)alloc((size_t)7 * 16384 * 2);
    float*          WRt    = (float*)alloc((size_t)7 * 128 * 4 * 4);
    float*          bias2  = (float*)alloc(32 * 4);
    int*            counts = (int*)alloc((size_t)N * 4);
    int*            tmp    = (int*)alloc((size_t)N * 4);
    int*            rp     = (int*)alloc((size_t)(N + 1) * 4);
    int*            bsum   = (int*)alloc(512 * 4);
    int*            boff   = (int*)alloc(512 * 4);
    float*          dinv   = (float*)alloc((size_t)N * 4);
    float*          invdeg = (float*)alloc((size_t)N * 4);
    int*            csrc   = (int*)alloc((size_t)E * 4);
    float*          cw     = (float*)alloc((size_t)E * 4);
    float*          uall   = (float*)alloc((size_t)N * 32 * 4);           // [N,32] fp32

    hipMemsetAsync(counts, 0, (size_t)N * 4, stream);
    hipMemsetAsync(tmp, 0, (size_t)N * 4, stream);

    int eb = (E + 255) / 256;
    int nb = (N + 255) / 256;
    k_count<<<eb, 256, 0, stream>>>(ei, counts, E);
    k_deg<<<nb, 256, 0, stream>>>(counts, dinv, invdeg, N);
    k_scan1<<<nb, 256, 0, stream>>>(counts, rp, bsum, N);
    k_scan2<<<1, 512, 0, stream>>>(bsum, boff, nb);
    k_scan3<<<nb, 256, 0, stream>>>(rp, boff, N, E);
    k_fill<<<eb, 256, 0, stream>>>(ei, dinv, rp, tmp, csrc, cw, E);
    k_xbf<<<(N * 64 + 255) / 256, 256, 0, stream>>>(x, xb, N * 64);
    k_wt<<<(7 * 16384 + 255) / 256, 256, 0, stream>>>(gw, Wt, 7 * 16384);
    k_wrt<<<4, 256, 0, stream>>>(gw, gb, r3w, r3b, r2w, r2b, WRt, bias2);
    k_px<<<(N + 3) / 4, 256, 0, stream>>>(xb, rp, csrc, cw, invdeg, pxb, N);
    dim3 gg((N + 31) / 32, 7);
    k_gemm<<<gg, 256, 0, stream>>>((const unsigned short*)pxb, Wt, gb, WRt, uall, N);
    k_out<<<(N + 3) / 4, 256, 0, stream>>>(uall, rp, csrc, cw, invdeg, bias2, out, N);
}

// Round 2
// 463.537 us; speedup vs baseline: 1.2735x; 1.2735x over previous
//
#include <hip/hip_runtime.h>

#define H 128

typedef __attribute__((ext_vector_type(8))) short bf16x8;
typedef __attribute__((ext_vector_type(4))) float f32x4;

__device__ __forceinline__ unsigned short f2bf(float f) {
    unsigned u = __float_as_uint(f);
    u += 0x7FFFu + ((u >> 16) & 1u);
    return (unsigned short)(u >> 16);
}
__device__ __forceinline__ float bflo(unsigned v) { return __uint_as_float(v << 16); }
__device__ __forceinline__ float bfhi(unsigned v) { return __uint_as_float(v & 0xFFFF0000u); }

// ---- CSR build ----------------------------------------------------------
__global__ void k_count(const int* __restrict__ ei, int* __restrict__ counts, int E) {
    int e = blockIdx.x * blockDim.x + threadIdx.x;
    if (e < E) atomicAdd(&counts[ei[E + e]], 1);
}

__global__ void k_deg(const int* __restrict__ counts, float* __restrict__ dinv,
                      float* __restrict__ invdeg, int N) {
    int i = blockIdx.x * blockDim.x + threadIdx.x;
    if (i < N) {
        float d = (float)(counts[i] + 1);
        dinv[i] = rsqrtf(d);
        invdeg[i] = 1.0f / d;
    }
}

__global__ void k_scan1(const int* __restrict__ counts, int* __restrict__ rp,
                        int* __restrict__ bsum, int N) {
    __shared__ int sh[256];
    int tid = threadIdx.x;
    int idx = blockIdx.x * 256 + tid;
    int v = (idx < N) ? counts[idx] : 0;
    sh[tid] = v;
    __syncthreads();
    for (int off = 1; off < 256; off <<= 1) {
        int t = (tid >= off) ? sh[tid - off] : 0;
        __syncthreads();
        sh[tid] += t;
        __syncthreads();
    }
    if (idx < N) rp[idx] = sh[tid] - v;
    if (tid == 255) bsum[blockIdx.x] = sh[tid];
}

__global__ void k_scan2(const int* __restrict__ bsum, int* __restrict__ boff, int nb) {
    __shared__ int sh[512];
    int tid = threadIdx.x;
    int v = (tid < nb) ? bsum[tid] : 0;
    sh[tid] = v;
    __syncthreads();
    for (int off = 1; off < 512; off <<= 1) {
        int t = (tid >= off) ? sh[tid - off] : 0;
        __syncthreads();
        sh[tid] += t;
        __syncthreads();
    }
    boff[tid] = sh[tid] - v;
}

__global__ void k_scan3(int* __restrict__ rp, const int* __restrict__ boff, int N, int E) {
    int idx = blockIdx.x * 256 + threadIdx.x;
    if (idx < N) rp[idx] += boff[blockIdx.x];
    if (idx == 0) rp[N] = E;
}

__global__ void k_fill(const int* __restrict__ ei, const float* __restrict__ dinv,
                       const int* __restrict__ rp, int* __restrict__ tmp,
                       int* __restrict__ csrc, float* __restrict__ cw, int E) {
    int e = blockIdx.x * blockDim.x + threadIdx.x;
    if (e < E) {
        int s = ei[e], d = ei[E + e];
        int p = rp[d] + atomicAdd(&tmp[d], 1);
        csrc[p] = s;
        cw[p] = dinv[s] * dinv[d];
    }
}

// ---- dtype prep ---------------------------------------------------------
__global__ void k_xbf(const float* __restrict__ x, unsigned* __restrict__ xb, int n2) {
    int i = blockIdx.x * blockDim.x + threadIdx.x;
    if (i < n2) {
        float2 v = ((const float2*)x)[i];
        xb[i] = (unsigned)f2bf(v.x) | ((unsigned)f2bf(v.y) << 16);
    }
}

// Wt[k][f_out][h_in] = W[k][h_in][f_out]  (bf16, so MFMA B-frags are contiguous)
__global__ void k_wt(const float* __restrict__ W, unsigned short* __restrict__ Wt, int total) {
    int idx = blockIdx.x * blockDim.x + threadIdx.x;
    if (idx < total) {
        int k = idx >> 14;
        int f = (idx >> 7) & 127;
        int h = idx & 127;
        Wt[(k << 14) + (h << 7) + f] = f2bf(W[idx]);
    }
}

// WRtb[k][c(16)][f(128)] bf16 = sum_h W[k][f][h]*R[k][c][h]  (c>=ck -> 0)
// bias2[k*4+c] = sum_h b[k][h]*R[k][c][h] + r[k][c]; pads zero
__global__ void k_wrt(const float* __restrict__ W, const float* __restrict__ b,
                      const float* __restrict__ r3w, const float* __restrict__ r3b,
                      const float* __restrict__ r2w, const float* __restrict__ r2b,
                      unsigned short* __restrict__ WRtb, float* __restrict__ bias2) {
    int tid = blockIdx.x * blockDim.x + threadIdx.x;
    if (tid < 14336) {
        int k = tid >> 11;
        int c = (tid >> 7) & 15;
        int f = tid & 127;
        int ck = (k < 5) ? 3 : 2;
        float s = 0.0f;
        if (c < ck) {
            const float* R = (k < 5) ? (r3w + (size_t)(k * 3 + c) * H)
                                     : (r2w + (size_t)((k - 5) * 2 + c) * H);
            const float* Wk = W + (k << 14) + (f << 7);
            for (int h = 0; h < H; ++h) s += Wk[h] * R[h];
        }
        WRtb[tid] = f2bf(s);
    } else if (tid < 14336 + 32) {
        int c32 = tid - 14336;
        int k = c32 >> 2, c = c32 & 3;
        int ck = (k < 5) ? 3 : 2;
        float t = 0.0f;
        if (c < ck) {
            const float* R = (k < 5) ? (r3w + (size_t)(k * 3 + c) * H)
                                     : (r2w + (size_t)((k - 5) * 2 + c) * H);
            const float* bk = b + k * H;
            for (int h = 0; h < H; ++h) t += bk[h] * R[h];
            t += (k < 5) ? r3b[k * 3 + c] : r2b[(k - 5) * 2 + c];
        }
        bias2[c32] = t;
    }
}

// ---- aggregation 1: px = P_hat @ x --------------------------------------
// wave per node; 16 lanes x 16B = one full row; 4 edges per load instruction
__global__ void __launch_bounds__(256) k_px(const unsigned* __restrict__ xb,
        const int* __restrict__ rp, const int* __restrict__ csrc,
        const float* __restrict__ cw, const float* __restrict__ invdeg,
        unsigned* __restrict__ pxb, int N) {
    int lane = threadIdx.x & 63;
    int wv = threadIdx.x >> 6;
    int i = blockIdx.x * 4 + wv;
    if (i >= N) return;
    int grp = lane >> 4, sub = lane & 15;
    int s = rp[i], e = rp[i + 1];
    float acc[8] = {0.f, 0.f, 0.f, 0.f, 0.f, 0.f, 0.f, 0.f};
    for (int base = s; base < e; base += 64) {
        int el = base + lane;
        bool ok = el < e;
        int j_l = ok ? csrc[el] : 0;
        float w_l = ok ? cw[el] : 0.0f;
        int cnt = e - base; if (cnt > 64) cnt = 64;
        for (int t = 0; t < cnt; t += 4) {
            int idx = t + grp;               // lanes with idx>=cnt carry w=0
            int jj = __shfl(j_l, idx);
            float ww = __shfl(w_l, idx);
            const uint4 v = *(const uint4*)(xb + (size_t)jj * 64 + sub * 4);
            acc[0] += ww * bflo(v.x); acc[1] += ww * bfhi(v.x);
            acc[2] += ww * bflo(v.y); acc[3] += ww * bfhi(v.y);
            acc[4] += ww * bflo(v.z); acc[5] += ww * bfhi(v.z);
            acc[6] += ww * bflo(v.w); acc[7] += ww * bfhi(v.w);
        }
    }
#pragma unroll
    for (int r = 0; r < 8; ++r) {
        acc[r] += __shfl_xor(acc[r], 16);
        acc[r] += __shfl_xor(acc[r], 32);
    }
    if (grp == 0) {
        const uint4 v = *(const uint4*)(xb + (size_t)i * 64 + sub * 4);
        float id = invdeg[i];
        uint4 o;
        o.x = (unsigned)f2bf(acc[0] + id * bflo(v.x)) | ((unsigned)f2bf(acc[1] + id * bfhi(v.x)) << 16);
        o.y = (unsigned)f2bf(acc[2] + id * bflo(v.y)) | ((unsigned)f2bf(acc[3] + id * bfhi(v.y)) << 16);
        o.z = (unsigned)f2bf(acc[4] + id * bflo(v.z)) | ((unsigned)f2bf(acc[5] + id * bfhi(v.z)) << 16);
        o.w = (unsigned)f2bf(acc[6] + id * bflo(v.w)) | ((unsigned)f2bf(acc[7] + id * bfhi(v.w)) << 16);
        *(uint4*)(pxb + (size_t)i * 64 + sub * 4) = o;
    }
}

// ---- GEMM: u = (relu(px@Wk + bk)) @ WRt_k via double MFMA ---------------
// 64-row tile per block, all 7 branches per block (A-frags reused)
__global__ void __launch_bounds__(256) k_gemm(const unsigned short* __restrict__ pxb,
        const unsigned short* __restrict__ Wt, const float* __restrict__ gb,
        const unsigned short* __restrict__ WRtb, float* __restrict__ uall, int N) {
    __shared__ __align__(16) unsigned short h1s[2][64][136];  // pad 136 spreads banks
    int bx = blockIdx.x;
    int wv = threadIdx.x >> 6;
    int lane = threadIdx.x & 63;
    int quad = lane >> 4, l16 = lane & 15;
    int row0 = bx * 64;
    bf16x8 af[4][4];
#pragma unroll
    for (int m = 0; m < 4; ++m) {
        int r = row0 + m * 16 + l16;
        if (r >= N) r = N - 1;
#pragma unroll
        for (int kk = 0; kk < 4; ++kk)
            af[m][kk] = *(const bf16x8*)(pxb + (size_t)r * H + kk * 32 + quad * 8);
    }
    int col0 = wv * 32 + l16;
    f32x4 uacc[7] = {};
#pragma unroll
    for (int k = 0; k < 7; ++k) {
        const unsigned short* B = Wt + (k << 14) + (size_t)col0 * H;
        f32x4 cacc[4][2] = {};
#pragma unroll
        for (int kk = 0; kk < 4; ++kk) {
            bf16x8 b0 = *(const bf16x8*)(B + kk * 32 + quad * 8);
            bf16x8 b1 = *(const bf16x8*)(B + 16 * H + kk * 32 + quad * 8);
#pragma unroll
            for (int m = 0; m < 4; ++m) {
                cacc[m][0] = __builtin_amdgcn_mfma_f32_16x16x32_bf16(af[m][kk], b0, cacc[m][0], 0, 0, 0);
                cacc[m][1] = __builtin_amdgcn_mfma_f32_16x16x32_bf16(af[m][kk], b1, cacc[m][1], 0, 0, 0);
            }
        }
        float bi0 = gb[k * H + col0], bi1 = gb[k * H + col0 + 16];
        int buf = k & 1;
#pragma unroll
        for (int m = 0; m < 4; ++m)
#pragma unroll
            for (int c = 0; c < 2; ++c) {
                float bb = c ? bi1 : bi0;
#pragma unroll
                for (int r = 0; r < 4; ++r)
                    h1s[buf][m * 16 + quad * 4 + r][wv * 32 + c * 16 + l16] =
                        f2bf(fmaxf(cacc[m][c][r] + bb, 0.0f));
            }
        __syncthreads();
        // second GEMM: wave wv handles 16-row tile wv; B = WRtb (cols 0-3 live)
        const unsigned short* Wr = WRtb + (k << 11);
#pragma unroll
        for (int kk = 0; kk < 4; ++kk) {
            bf16x8 ah = *(const bf16x8*)(&h1s[buf][wv * 16 + l16][kk * 32 + quad * 8]);
            bf16x8 bw = *(const bf16x8*)(Wr + l16 * 128 + kk * 32 + quad * 8);
            uacc[k] = __builtin_amdgcn_mfma_f32_16x16x32_bf16(ah, bw, uacc[k], 0, 0, 0);
        }
    }
    if (l16 < 4) {
#pragma unroll
        for (int k = 0; k < 7; ++k)
#pragma unroll
            for (int r = 0; r < 4; ++r) {
                int row = row0 + wv * 16 + quad * 4 + r;
                if (row < N) uall[(size_t)row * 32 + k * 4 + l16] = uacc[k][r];
            }
    }
}

// ---- aggregation 2 + softmax -------------------------------------------
// wave per node; 8 lanes x 16B = one full 128B row; 8 edges per load instr
__global__ void __launch_bounds__(256) k_out(const float* __restrict__ uall,
        const int* __restrict__ rp, const int* __restrict__ csrc,
        const float* __restrict__ cw, const float* __restrict__ invdeg,
        const float* __restrict__ bias2, float* __restrict__ out, int N) {
    int lane = threadIdx.x & 63;
    int wv = threadIdx.x >> 6;
    int i = blockIdx.x * 4 + wv;
    if (i >= N) return;
    int grp = lane >> 3, sub = lane & 7;
    int s = rp[i], e = rp[i + 1];
    float a0 = 0.f, a1 = 0.f, a2 = 0.f, a3 = 0.f;
    for (int base = s; base < e; base += 64) {
        int el = base + lane;
        bool ok = el < e;
        int j_l = ok ? csrc[el] : 0;
        float w_l = ok ? cw[el] : 0.0f;
        int cnt = e - base; if (cnt > 64) cnt = 64;
        for (int t = 0; t < cnt; t += 8) {
            int idx = t + grp;
            int jj = __shfl(j_l, idx);
            float ww = __shfl(w_l, idx);
            const float4 v = *(const float4*)(uall + (size_t)jj * 32 + sub * 4);
            a0 += ww * v.x; a1 += ww * v.y; a2 += ww * v.z; a3 += ww * v.w;
        }
    }
#pragma unroll
    for (int m = 8; m <= 32; m <<= 1) {
        a0 += __shfl_xor(a0, m); a1 += __shfl_xor(a1, m);
        a2 += __shfl_xor(a2, m); a3 += __shfl_xor(a3, m);
    }
    if (grp == 0 && sub < 7) {
        int b = sub;
        const float4 v = *(const float4*)(uall + (size_t)i * 32 + b * 4);
        float id = invdeg[i];
        float v0 = a0 + id * v.x + bias2[b * 4 + 0];
        float v1 = a1 + id * v.y + bias2[b * 4 + 1];
        float v2 = a2 + id * v.z + bias2[b * 4 + 2];
        int ck = (b < 5) ? 3 : 2;
        float mx = fmaxf(v0, v1);
        if (ck == 3) mx = fmaxf(mx, v2);
        float e0 = __expf(v0 - mx), e1 = __expf(v1 - mx);
        float e2 = (ck == 3) ? __expf(v2 - mx) : 0.0f;
        float inv = 1.0f / (e0 + e1 + e2);
        size_t basek = (b < 5) ? (size_t)b * 3 * N + (size_t)i * 3
                               : (size_t)15 * N + (size_t)(b - 5) * 2 * N + (size_t)i * 2;
        out[basek + 0] = e0 * inv;
        out[basek + 1] = e1 * inv;
        if (ck == 3) out[basek + 2] = e2 * inv;
    }
}

// ---- launch -------------------------------------------------------------
extern "C" void kernel_launch(void* const* d_in, const int* in_sizes, int n_in,
                              void* d_out, int out_size, void* d_ws, size_t ws_size,
                              hipStream_t stream) {
    (void)n_in; (void)out_size; (void)ws_size;
    const float* x   = (const float*)d_in[0];
    const int*   ei  = (const int*)d_in[1];
    const float* gw  = (const float*)d_in[2];
    const float* gb  = (const float*)d_in[3];
    const float* r3w = (const float*)d_in[4];
    const float* r3b = (const float*)d_in[5];
    const float* r2w = (const float*)d_in[6];
    const float* r2b = (const float*)d_in[7];
    float* out = (float*)d_out;
    int N = in_sizes[0] / H;   // 100000
    int E = in_sizes[1] / 2;   // 1600000

    char* p = (char*)d_ws;
    auto alloc = [&](size_t bytes) {
        char* q = p;
        p += (bytes + 255) & ~(size_t)255;
        return q;
    };
    unsigned*       xb     = (unsigned*)alloc((size_t)N * 64 * 4);
    unsigned*       pxb    = (unsigned*)alloc((size_t)N * 64 * 4);
    unsigned short* Wt     = (unsigned short*)alloc((size_t)7 * 16384 * 2);
    unsigned short* WRtb   = (unsigned short*)alloc((size_t)7 * 2048 * 2);
    float*          bias2  = (float*)alloc(32 * 4);
    int*            counts = (int*)alloc((size_t)N * 4);
    int*            tmp    = (int*)alloc((size_t)N * 4);
    int*            rp     = (int*)alloc((size_t)(N + 1) * 4);
    int*            bsum   = (int*)alloc(512 * 4);
    int*            boff   = (int*)alloc(512 * 4);
    float*          dinv   = (float*)alloc((size_t)N * 4);
    float*          invdeg = (float*)alloc((size_t)N * 4);
    int*            csrc   = (int*)alloc((size_t)E * 4);
    float*          cw     = (float*)alloc((size_t)E * 4);
    float*          uall   = (float*)alloc((size_t)N * 32 * 4);

    hipMemsetAsync(counts, 0, (size_t)N * 4, stream);
    hipMemsetAsync(tmp, 0, (size_t)N * 4, stream);

    int eb = (E + 255) / 256;
    int nb = (N + 255) / 256;
    k_count<<<eb, 256, 0, stream>>>(ei, counts, E);
    k_deg<<<nb, 256, 0, stream>>>(counts, dinv, invdeg, N);
    k_scan1<<<nb, 256, 0, stream>>>(counts, rp, bsum, N);
    k_scan2<<<1, 512, 0, stream>>>(bsum, boff, nb);
    k_scan3<<<nb, 256, 0, stream>>>(rp, boff, N, E);
    k_fill<<<eb, 256, 0, stream>>>(ei, dinv, rp, tmp, csrc, cw, E);
    k_xbf<<<(N * 64 + 255) / 256, 256, 0, stream>>>(x, xb, N * 64);
    k_wt<<<(7 * 16384 + 255) / 256, 256, 0, stream>>>(gw, Wt, 7 * 16384);
    k_wrt<<<(14368 + 255) / 256, 256, 0, stream>>>(gw, gb, r3w, r3b, r2w, r2b, WRtb, bias2);
    k_px<<<(N + 3) / 4, 256, 0, stream>>>(xb, rp, csrc, cw, invdeg, pxb, N);
    k_gemm<<<(N + 63) / 64, 256, 0, stream>>>((const unsigned short*)pxb, Wt, gb, WRtb, uall, N);
    k_out<<<(N + 3) / 4, 256, 0, stream>>>(uall, rp, csrc, cw, invdeg, bias2, out, N);
}

// Round 3
// 376.896 us; speedup vs baseline: 1.5662x; 1.2299x over previous
//
#include <hip/hip_runtime.h>

#define H 128

typedef __attribute__((ext_vector_type(8))) short bf16x8;
typedef __attribute__((ext_vector_type(4))) float f32x4;

__device__ __forceinline__ unsigned short f2bf(float f) {
    unsigned u = __float_as_uint(f);
    u += 0x7FFFu + ((u >> 16) & 1u);
    return (unsigned short)(u >> 16);
}
__device__ __forceinline__ float bflo(unsigned v) { return __uint_as_float(v << 16); }
__device__ __forceinline__ float bfhi(unsigned v) { return __uint_as_float(v & 0xFFFF0000u); }

// ---- CSR build via 2-level bucket sort ----------------------------------
// bucket b covers nodes [b*256, b*256+256)

__global__ void __launch_bounds__(256) k_bhist(const int* __restrict__ ei,
                                               int* __restrict__ bhist, int E) {
    __shared__ int h[512];
    int t = threadIdx.x;
    h[t] = 0; h[t + 256] = 0;
    __syncthreads();
    int stride = gridDim.x * 256;
    for (int e = blockIdx.x * 256 + t; e < E; e += stride)
        atomicAdd(&h[ei[E + e] >> 8], 1);
    __syncthreads();
    for (int u = t; u < 512; u += 256) {
        int v = h[u];
        if (v) atomicAdd(&bhist[u], v);
    }
}

__global__ void k_bscan(const int* __restrict__ bhist, int* __restrict__ bbase,
                        int* __restrict__ gcur) {
    __shared__ int sh[512];
    int t = threadIdx.x;
    int v = bhist[t];
    sh[t] = v;
    __syncthreads();
    for (int off = 1; off < 512; off <<= 1) {
        int u = (t >= off) ? sh[t - off] : 0;
        __syncthreads();
        sh[t] += u;
        __syncthreads();
    }
    int ex = sh[t] - v;
    bbase[t] = ex;
    gcur[t] = ex;
    if (t == 511) bbase[512] = sh[t];   // = E
}

// scatter {src,dst} into bucket regions; per-block LDS histogram + one
// global atomic per (block,bucket) keeps appends contiguous
__global__ void __launch_bounds__(256) k_scatter(const int* __restrict__ ei,
        int* __restrict__ gcur, int2* __restrict__ tmp_sd, int E) {
    __shared__ int hist[512], base[512], fill[512];
    int blk = blockIdx.x, t = threadIdx.x;
    int chunk = (E + gridDim.x - 1) / gridDim.x;
    int c0 = blk * chunk;
    int c1 = c0 + chunk; if (c1 > E) c1 = E;
    hist[t] = 0; hist[t + 256] = 0;
    __syncthreads();
    for (int e = c0 + t; e < c1; e += 256)
        atomicAdd(&hist[ei[E + e] >> 8], 1);
    __syncthreads();
    for (int u = t; u < 512; u += 256) {
        int h = hist[u];
        base[u] = h ? atomicAdd(&gcur[u], h) : 0;
        fill[u] = 0;
    }
    __syncthreads();
    for (int e = c0 + t; e < c1; e += 256) {
        int d = ei[E + e], s = ei[e];
        int bb = d >> 8;
        int p = base[bb] + atomicAdd(&fill[bb], 1);
        tmp_sd[p] = make_int2(s, d);
    }
}

// per-bucket: local count + scan -> rp, dinv, invdeg
__global__ void __launch_bounds__(256) k_csrA(const int2* __restrict__ tmp_sd,
        const int* __restrict__ bbase, int* __restrict__ rp,
        float* __restrict__ dinv, float* __restrict__ invdeg, int N, int E) {
    __shared__ int cnt[256];
    __shared__ int sh[256];
    int b = blockIdx.x, t = threadIdx.x;
    int e0 = bbase[b], e1 = bbase[b + 1];
    cnt[t] = 0;
    __syncthreads();
    for (int e = e0 + t; e < e1; e += 256)
        atomicAdd(&cnt[tmp_sd[e].y & 255], 1);
    __syncthreads();
    int v = cnt[t];
    sh[t] = v;
    __syncthreads();
    for (int off = 1; off < 256; off <<= 1) {
        int u = (t >= off) ? sh[t - off] : 0;
        __syncthreads();
        sh[t] += u;
        __syncthreads();
    }
    int gid = (b << 8) + t;
    if (gid < N) {
        rp[gid] = e0 + sh[t] - v;
        float dg = (float)(v + 1);
        dinv[gid] = rsqrtf(dg);
        invdeg[gid] = 1.0f / dg;
    }
    if (b == 0 && t == 0) rp[N] = E;
}

// per-bucket: scatter to final CSR position; writes stay in a ~32KB region
__global__ void __launch_bounds__(256) k_csrB(const int2* __restrict__ tmp_sd,
        const int* __restrict__ bbase, const int* __restrict__ rp,
        const float* __restrict__ dinv, int* __restrict__ csrc,
        float* __restrict__ cw, int N) {
    __shared__ int fill[256];
    __shared__ float ld[256];
    int b = blockIdx.x, t = threadIdx.x;
    int e0 = bbase[b], e1 = bbase[b + 1];
    int gid = (b << 8) + t;
    fill[t] = (gid < N) ? rp[gid] : 0;
    ld[t] = (gid < N) ? dinv[gid] : 0.0f;
    __syncthreads();
    for (int e = e0 + t; e < e1; e += 256) {
        int2 sd = tmp_sd[e];
        int l = sd.y & 255;
        int p = atomicAdd(&fill[l], 1);
        csrc[p] = sd.x;
        cw[p] = dinv[sd.x] * ld[l];
    }
}

// ---- dtype prep ---------------------------------------------------------
__global__ void k_xbf(const float* __restrict__ x, unsigned* __restrict__ xb, int n2) {
    int i = blockIdx.x * blockDim.x + threadIdx.x;
    if (i < n2) {
        float2 v = ((const float2*)x)[i];
        xb[i] = (unsigned)f2bf(v.x) | ((unsigned)f2bf(v.y) << 16);
    }
}

// Wt[k][f_out][h_in] = W[k][h_in][f_out]  (bf16, MFMA B-frags contiguous)
__global__ void k_wt(const float* __restrict__ W, unsigned short* __restrict__ Wt, int total) {
    int idx = blockIdx.x * blockDim.x + threadIdx.x;
    if (idx < total) {
        int k = idx >> 14;
        int f = (idx >> 7) & 127;
        int h = idx & 127;
        Wt[(k << 14) + (h << 7) + f] = f2bf(W[idx]);
    }
}

// WRtbP[k][c(16)][fp(128)] bf16, with the f-dimension PERMUTED to match the
// packed h1 LDS layout: within each 32-group, fp=2*t+h  <->  orig f=t+16*h.
// bias2[k*4+c] = b_k @ R_k^T + r_k
__global__ void k_wrt(const float* __restrict__ W, const float* __restrict__ b,
                      const float* __restrict__ r3w, const float* __restrict__ r3b,
                      const float* __restrict__ r2w, const float* __restrict__ r2b,
                      unsigned short* __restrict__ WRtbP, float* __restrict__ bias2) {
    int tid = blockIdx.x * blockDim.x + threadIdx.x;
    if (tid < 14336) {
        int k = tid >> 11;
        int c = (tid >> 7) & 15;
        int fp = tid & 127;
        int g = fp >> 5, off = fp & 31;
        int f = (g << 5) + (off >> 1) + ((off & 1) << 4);   // un-permute
        int ck = (k < 5) ? 3 : 2;
        float s = 0.0f;
        if (c < ck) {
            const float* R = (k < 5) ? (r3w + (size_t)(k * 3 + c) * H)
                                     : (r2w + (size_t)((k - 5) * 2 + c) * H);
            const float* Wk = W + (k << 14) + (f << 7);
            for (int h = 0; h < H; ++h) s += Wk[h] * R[h];
        }
        WRtbP[tid] = f2bf(s);
    } else if (tid < 14336 + 32) {
        int c32 = tid - 14336;
        int k = c32 >> 2, c = c32 & 3;
        int ck = (k < 5) ? 3 : 2;
        float t = 0.0f;
        if (c < ck) {
            const float* R = (k < 5) ? (r3w + (size_t)(k * 3 + c) * H)
                                     : (r2w + (size_t)((k - 5) * 2 + c) * H);
            const float* bk = b + k * H;
            for (int h = 0; h < H; ++h) t += bk[h] * R[h];
            t += (k < 5) ? r3b[k * 3 + c] : r2b[(k - 5) * 2 + c];
        }
        bias2[c32] = t;
    }
}

// ---- aggregation 1: px = P_hat @ x --------------------------------------
__global__ void __launch_bounds__(256) k_px(const unsigned* __restrict__ xb,
        const int* __restrict__ rp, const int* __restrict__ csrc,
        const float* __restrict__ cw, const float* __restrict__ invdeg,
        unsigned* __restrict__ pxb, int N) {
    int lane = threadIdx.x & 63;
    int wv = threadIdx.x >> 6;
    int i = blockIdx.x * 4 + wv;
    if (i >= N) return;
    int grp = lane >> 4, sub = lane & 15;
    int s = rp[i], e = rp[i + 1];
    float acc[8] = {0.f, 0.f, 0.f, 0.f, 0.f, 0.f, 0.f, 0.f};
    for (int base = s; base < e; base += 64) {
        int el = base + lane;
        bool ok = el < e;
        int j_l = ok ? csrc[el] : 0;
        float w_l = ok ? cw[el] : 0.0f;
        int cnt = e - base; if (cnt > 64) cnt = 64;
        for (int t = 0; t < cnt; t += 4) {
            int idx = t + grp;
            int jj = __shfl(j_l, idx);
            float ww = __shfl(w_l, idx);
            const uint4 v = *(const uint4*)(xb + (size_t)jj * 64 + sub * 4);
            acc[0] += ww * bflo(v.x); acc[1] += ww * bfhi(v.x);
            acc[2] += ww * bflo(v.y); acc[3] += ww * bfhi(v.y);
            acc[4] += ww * bflo(v.z); acc[5] += ww * bfhi(v.z);
            acc[6] += ww * bflo(v.w); acc[7] += ww * bfhi(v.w);
        }
    }
#pragma unroll
    for (int r = 0; r < 8; ++r) {
        acc[r] += __shfl_xor(acc[r], 16);
        acc[r] += __shfl_xor(acc[r], 32);
    }
    if (grp == 0) {
        const uint4 v = *(const uint4*)(xb + (size_t)i * 64 + sub * 4);
        float id = invdeg[i];
        uint4 o;
        o.x = (unsigned)f2bf(acc[0] + id * bflo(v.x)) | ((unsigned)f2bf(acc[1] + id * bfhi(v.x)) << 16);
        o.y = (unsigned)f2bf(acc[2] + id * bflo(v.y)) | ((unsigned)f2bf(acc[3] + id * bfhi(v.y)) << 16);
        o.z = (unsigned)f2bf(acc[4] + id * bflo(v.z)) | ((unsigned)f2bf(acc[5] + id * bfhi(v.z)) << 16);
        o.w = (unsigned)f2bf(acc[6] + id * bflo(v.w)) | ((unsigned)f2bf(acc[7] + id * bfhi(v.w)) << 16);
        *(uint4*)(pxb + (size_t)i * 64 + sub * 4) = o;
    }
}

// ---- GEMM: u = (relu(px@Wk + bk)) @ WRt_k via double MFMA ---------------
// 64-row tile per block, all 7 branches per block (A-frags register-resident)
// h1 stored packed (2 cols per b32) in permuted K-order; row stride 144
// shorts = 72 words keeps 16B alignment, 4-way max read aliasing.
__global__ void __launch_bounds__(256) k_gemm(const unsigned short* __restrict__ pxb,
        const unsigned short* __restrict__ Wt, const float* __restrict__ gb,
        const unsigned short* __restrict__ WRtbP, float* __restrict__ uall, int N) {
    __shared__ __align__(16) unsigned short h1s[2][64][144];
    int bx = blockIdx.x;
    int wv = threadIdx.x >> 6;
    int lane = threadIdx.x & 63;
    int quad = lane >> 4, l16 = lane & 15;
    int row0 = bx * 64;
    bf16x8 af[4][4];
#pragma unroll
    for (int m = 0; m < 4; ++m) {
        int r = row0 + m * 16 + l16;
        if (r >= N) r = N - 1;
#pragma unroll
        for (int kk = 0; kk < 4; ++kk)
            af[m][kk] = *(const bf16x8*)(pxb + (size_t)r * H + kk * 32 + quad * 8);
    }
    int col0 = wv * 32 + l16;
    f32x4 uacc[7] = {};
#pragma unroll
    for (int k = 0; k < 7; ++k) {
        const unsigned short* B = Wt + (k << 14) + (size_t)col0 * H;
        f32x4 cacc[4][2] = {};
#pragma unroll
        for (int kk = 0; kk < 4; ++kk) {
            bf16x8 b0 = *(const bf16x8*)(B + kk * 32 + quad * 8);
            bf16x8 b1 = *(const bf16x8*)(B + 16 * H + kk * 32 + quad * 8);
#pragma unroll
            for (int m = 0; m < 4; ++m) {
                cacc[m][0] = __builtin_amdgcn_mfma_f32_16x16x32_bf16(af[m][kk], b0, cacc[m][0], 0, 0, 0);
                cacc[m][1] = __builtin_amdgcn_mfma_f32_16x16x32_bf16(af[m][kk], b1, cacc[m][1], 0, 0, 0);
            }
        }
        float bi0 = gb[k * H + col0], bi1 = gb[k * H + col0 + 16];
        int buf = k & 1;
        unsigned* dstw = (unsigned*)&h1s[buf][0][0];
#pragma unroll
        for (int m = 0; m < 4; ++m)
#pragma unroll
            for (int r = 0; r < 4; ++r) {
                float h0 = fmaxf(cacc[m][0][r] + bi0, 0.0f);
                float h1v = fmaxf(cacc[m][1][r] + bi1, 0.0f);
                unsigned pk = (unsigned)f2bf(h0) | ((unsigned)f2bf(h1v) << 16);
                dstw[(m * 16 + quad * 4 + r) * 72 + wv * 16 + l16] = pk;
            }
        __syncthreads();
        const unsigned short* Wr = WRtbP + (k << 11);
#pragma unroll
        for (int kk = 0; kk < 4; ++kk) {
            bf16x8 ah = *(const bf16x8*)(&h1s[buf][wv * 16 + l16][kk * 32 + quad * 8]);
            bf16x8 bw = *(const bf16x8*)(Wr + l16 * 128 + kk * 32 + quad * 8);
            uacc[k] = __builtin_amdgcn_mfma_f32_16x16x32_bf16(ah, bw, uacc[k], 0, 0, 0);
        }
    }
    if (l16 < 4) {
#pragma unroll
        for (int k = 0; k < 7; ++k)
#pragma unroll
            for (int r = 0; r < 4; ++r) {
                int row = row0 + wv * 16 + quad * 4 + r;
                if (row < N) uall[(size_t)row * 32 + k * 4 + l16] = uacc[k][r];
            }
    }
}

// ---- aggregation 2 + softmax -------------------------------------------
__global__ void __launch_bounds__(256) k_out(const float* __restrict__ uall,
        const int* __restrict__ rp, const int* __restrict__ csrc,
        const float* __restrict__ cw, const float* __restrict__ invdeg,
        const float* __restrict__ bias2, float* __restrict__ out, int N) {
    int lane = threadIdx.x & 63;
    int wv = threadIdx.x >> 6;
    int i = blockIdx.x * 4 + wv;
    if (i >= N) return;
    int grp = lane >> 3, sub = lane & 7;
    int s = rp[i], e = rp[i + 1];
    float a0 = 0.f, a1 = 0.f, a2 = 0.f, a3 = 0.f;
    for (int base = s; base < e; base += 64) {
        int el = base + lane;
        bool ok = el < e;
        int j_l = ok ? csrc[el] : 0;
        float w_l = ok ? cw[el] : 0.0f;
        int cnt = e - base; if (cnt > 64) cnt = 64;
        for (int t = 0; t < cnt; t += 8) {
            int idx = t + grp;
            int jj = __shfl(j_l, idx);
            float ww = __shfl(w_l, idx);
            const float4 v = *(const float4*)(uall + (size_t)jj * 32 + sub * 4);
            a0 += ww * v.x; a1 += ww * v.y; a2 += ww * v.z; a3 += ww * v.w;
        }
    }
#pragma unroll
    for (int m = 8; m <= 32; m <<= 1) {
        a0 += __shfl_xor(a0, m); a1 += __shfl_xor(a1, m);
        a2 += __shfl_xor(a2, m); a3 += __shfl_xor(a3, m);
    }
    if (grp == 0 && sub < 7) {
        int b = sub;
        const float4 v = *(const float4*)(uall + (size_t)i * 32 + b * 4);
        float id = invdeg[i];
        float v0 = a0 + id * v.x + bias2[b * 4 + 0];
        float v1 = a1 + id * v.y + bias2[b * 4 + 1];
        float v2 = a2 + id * v.z + bias2[b * 4 + 2];
        int ck = (b < 5) ? 3 : 2;
        float mx = fmaxf(v0, v1);
        if (ck == 3) mx = fmaxf(mx, v2);
        float e0 = __expf(v0 - mx), e1 = __expf(v1 - mx);
        float e2 = (ck == 3) ? __expf(v2 - mx) : 0.0f;
        float inv = 1.0f / (e0 + e1 + e2);
        size_t basek = (b < 5) ? (size_t)b * 3 * N + (size_t)i * 3
                               : (size_t)15 * N + (size_t)(b - 5) * 2 * N + (size_t)i * 2;
        out[basek + 0] = e0 * inv;
        out[basek + 1] = e1 * inv;
        if (ck == 3) out[basek + 2] = e2 * inv;
    }
}

// ---- launch -------------------------------------------------------------
extern "C" void kernel_launch(void* const* d_in, const int* in_sizes, int n_in,
                              void* d_out, int out_size, void* d_ws, size_t ws_size,
                              hipStream_t stream) {
    (void)n_in; (void)out_size; (void)ws_size;
    const float* x   = (const float*)d_in[0];
    const int*   ei  = (const int*)d_in[1];
    const float* gw  = (const float*)d_in[2];
    const float* gb  = (const float*)d_in[3];
    const float* r3w = (const float*)d_in[4];
    const float* r3b = (const float*)d_in[5];
    const float* r2w = (const float*)d_in[6];
    const float* r2b = (const float*)d_in[7];
    float* out = (float*)d_out;
    int N = in_sizes[0] / H;   // 100000
    int E = in_sizes[1] / 2;   // 1600000
    int NB = (N + 255) >> 8;   // 391 buckets

    char* p = (char*)d_ws;
    auto alloc = [&](size_t bytes) {
        char* q = p;
        p += (bytes + 255) & ~(size_t)255;
        return q;
    };
    unsigned*       xb     = (unsigned*)alloc((size_t)N * 64 * 4);
    unsigned*       pxb    = (unsigned*)alloc((size_t)N * 64 * 4);
    unsigned short* Wt     = (unsigned short*)alloc((size_t)7 * 16384 * 2);
    unsigned short* WRtbP  = (unsigned short*)alloc((size_t)7 * 2048 * 2);
    float*          bias2  = (float*)alloc(32 * 4);
    int*            bhist  = (int*)alloc(512 * 4);
    int*            bbase  = (int*)alloc(513 * 4);
    int*            gcur   = (int*)alloc(512 * 4);
    int2*           tmp_sd = (int2*)alloc((size_t)E * 8);
    int*            rp     = (int*)alloc((size_t)(N + 1) * 4);
    float*          dinv   = (float*)alloc((size_t)N * 4);
    float*          invdeg = (float*)alloc((size_t)N * 4);
    int*            csrc   = (int*)alloc((size_t)E * 4);
    float*          cw     = (float*)alloc((size_t)E * 4);
    float*          uall   = (float*)alloc((size_t)N * 32 * 4);

    hipMemsetAsync(bhist, 0, 512 * 4, stream);
    k_bhist<<<256, 256, 0, stream>>>(ei, bhist, E);
    k_bscan<<<1, 512, 0, stream>>>(bhist, bbase, gcur);
    k_scatter<<<256, 256, 0, stream>>>(ei, gcur, tmp_sd, E);
    k_csrA<<<NB, 256, 0, stream>>>(tmp_sd, bbase, rp, dinv, invdeg, N, E);
    k_csrB<<<NB, 256, 0, stream>>>(tmp_sd, bbase, rp, dinv, csrc, cw, N);
    k_xbf<<<(N * 64 + 255) / 256, 256, 0, stream>>>(x, xb, N * 64);
    k_wt<<<(7 * 16384 + 255) / 256, 256, 0, stream>>>(gw, Wt, 7 * 16384);
    k_wrt<<<(14368 + 255) / 256, 256, 0, stream>>>(gw, gb, r3w, r3b, r2w, r2b, WRtbP, bias2);
    k_px<<<(N + 3) / 4, 256, 0, stream>>>(xb, rp, csrc, cw, invdeg, pxb, N);
    k_gemm<<<(N + 63) / 64, 256, 0, stream>>>((const unsigned short*)pxb, Wt, gb, WRtbP, uall, N);
    k_out<<<(N + 3) / 4, 256, 0, stream>>>(uall, rp, csrc, cw, invdeg, bias2, out, N);
}